// Round 21
// baseline (65.613 us; speedup 1.0000x reference)
//
#include <hip/hip_runtime.h>
#include <hip/hip_bf16.h>

#define NN 512
#define DD 128

typedef __bf16 bf16x8 __attribute__((ext_vector_type(8)));
typedef float f32x4 __attribute__((ext_vector_type(4)));

static __device__ __forceinline__ f32x4 mfma16(bf16x8 a, bf16x8 b, f32x4 c) {
  return __builtin_amdgcn_mfma_f32_16x16x32_bf16(a, b, c, 0, 0, 0);
}

// -------- phase 0 (fused): w1t transpose + hjp + cnt --------
__global__ void k_pre(const float* __restrict__ h,
                      const float* __restrict__ msg_w1,
                      const float* __restrict__ msg_b1,
                      const int* __restrict__ emask,
                      __bf16* __restrict__ w1t, float* __restrict__ hjp,
                      float* __restrict__ cnt) {
  __shared__ float hr[128];
  __shared__ int csum;
  int j = blockIdx.x, t = threadIdx.x;
  if (t == 0) csum = 0;
  hr[t] = h[j * 128 + t];
  __syncthreads();
  float a0 = msg_b1[t], a1 = 0.f;
  #pragma unroll 16
  for (int k = 0; k < 128; k += 2) {
    a0 += hr[k] * msg_w1[k * 128 + t];
    a1 += hr[k + 1] * msg_w1[(k + 1) * 128 + t];
  }
  hjp[j * 128 + t] = a0 + a1;
  // w1t[e][k] = msg_w1[128+k][e] : 32 elements per block
  if (t < 32) {
    int tt = j * 32 + t;
    int e = tt >> 7, k = tt & 127;
    w1t[e * 128 + k] = (__bf16)msg_w1[(128 + k) * 128 + e];
  }
  // cnt[j] = sum_r emask[r][j]
  int s = 0;
  #pragma unroll
  for (int r = 0; r < 4; r++) s += emask[(t * 4 + r) * NN + j] ? 1 : 0;
  #pragma unroll
  for (int off = 32; off > 0; off >>= 1) s += __shfl_down(s, off, 64);
  if ((t & 63) == 0) atomicAdd(&csum, s);
  __syncthreads();
  if (t == 0) cnt[j] = (float)csum;
}

// ---------------- phase 1: T[i][e] = sum_j mask[j,i]*silu(pre[j,i,e]) ----
// BARRIER-FREE k_main. R19's 43.1us floor was the per-step __syncthreads
// draining vmcnt/lgkmcnt for all waves (overlap factor ~0.47 across HBM
// ~11us / LDS ~9us / VALU ~5us per-CU pipes). Observation: a wave's 64
// lanes (q,l15) read the FULL 16-row rel tile exactly once directly --
// lane reads row irow+l15, byte chunks q*32+{0,128,256,384} (+16B) ->
// 16 x 64B segments per instr, fully coalesced. So: NO LDS, NO barriers;
// each wave loads its own B-fragments global->reg (predicated by a
// prologue bitmask -- masked rows fetched by NO wave), cvts in-register,
// MFMAs. 4 waves/block re-read the same tile -> L2/L1 serve 3 of 4
// (masked volume ~8us/CU < HBM 11us). Zero sync => wave-skew TLP +
// depth-2 X/Y register pipeline (static names, rule #20) overlap pipes.
// Stale regs finite + MFMA column-independence => ms=0 masks exactly.
// (256,2) = cap 256, the only spill-free cap (R1-R10 allocator law);
// peak live ~160 VGPR.
#define CVT(bf, xa, xb) { \
  bf[0] = (__bf16)xa[0]; bf[1] = (__bf16)xa[1]; \
  bf[2] = (__bf16)xa[2]; bf[3] = (__bf16)xa[3]; \
  bf[4] = (__bf16)xb[0]; bf[5] = (__bf16)xb[1]; \
  bf[6] = (__bf16)xb[2]; bf[7] = (__bf16)xb[3]; }

__global__ __launch_bounds__(256, 2) void k_main(
    const float* __restrict__ rel, const int* __restrict__ emask,
    const float* __restrict__ hjp, const __bf16* __restrict__ w1t_g,
    float* __restrict__ partial) {
  const int tid = threadIdx.x;
  const int wave = tid >> 6;
  const int lane = tid & 63;
  const int l15 = lane & 15;
  const int q = lane >> 4;

  const int it = blockIdx.x >> 5;    // 0..31 : 16-row i-tile
  const int jc = blockIdx.x & 31;    // 0..31 : 16-col j-chunk
  const int irow = it * 16;
  const int jbase = jc * 16;

  // wave-private w1 fragments for e-slice [32w, 32w+32)
  bf16x8 aw00, aw01, aw02, aw03, aw10, aw11, aw12, aw13;
  {
    const __bf16* b0 = w1t_g + (wave * 32 + l15) * 128 + q * 8;
    aw00 = *(const bf16x8*)(b0);
    aw01 = *(const bf16x8*)(b0 + 32);
    aw02 = *(const bf16x8*)(b0 + 64);
    aw03 = *(const bf16x8*)(b0 + 96);
    const __bf16* b1 = b0 + 16 * 128;
    aw10 = *(const bf16x8*)(b1);
    aw11 = *(const bf16x8*)(b1 + 32);
    aw12 = *(const bf16x8*)(b1 + 64);
    aw13 = *(const bf16x8*)(b1 + 96);
  }

  // per-lane row mask bitmask: bit jr = emask[jbase+jr][irow+l15]
  unsigned msk = 0;
  #pragma unroll
  for (int jr = 0; jr < 16; jr++)
    msk |= (emask[(size_t)(jbase + jr) * NN + irow + l15] ? (1u << jr) : 0u);

  // t0[r] = T[i=l15][e=32w+q*4+r], t1 = +16
  f32x4 t0 = {0.f, 0.f, 0.f, 0.f}, t1 = t0;

  // this lane's B-fragment base: row irow+l15, float offset q*8
  const float* rb = rel + ((size_t)jbase * NN + irow + l15) * DD + q * 8;

  // X/Y register sets (8 x f32x4 each), zeroed once: stale contents are
  // always finite; ms=0 masks their contributions exactly.
  f32x4 X0 = {0.f, 0.f, 0.f, 0.f}, X1 = X0, X2 = X0, X3 = X0,
        X4 = X0, X5 = X0, X6 = X0, X7 = X0;
  f32x4 Y0 = X0, Y1 = X0, Y2 = X0, Y3 = X0,
        Y4 = X0, Y5 = X0, Y6 = X0, Y7 = X0;

  #define LOADSET(J, S0, S1, S2, S3, S4, S5, S6, S7) \
    if ((msk >> (J)) & 1) { \
      const float* s = rb + (size_t)(J) * (NN * DD); \
      S0 = *(const f32x4*)(s);      S1 = *(const f32x4*)(s + 4); \
      S2 = *(const f32x4*)(s + 32); S3 = *(const f32x4*)(s + 36); \
      S4 = *(const f32x4*)(s + 64); S5 = *(const f32x4*)(s + 68); \
      S6 = *(const f32x4*)(s + 96); S7 = *(const f32x4*)(s + 100); \
    }

  // prologue: rows 0 -> X, 1 -> Y
  LOADSET(0, X0, X1, X2, X3, X4, X5, X6, X7)
  LOADSET(1, Y0, Y1, Y2, Y3, Y4, Y5, Y6, Y7)

  // STEP: cvt set -> bf regs (frees set), reload set with row JR+2,
  // hv issued pre-chain / consumed post-chain, MFMA chain, silu, accum.
  #define STEP(JR, S0, S1, S2, S3, S4, S5, S6, S7) { \
    bf16x8 b0, b1, b2, b3; \
    CVT(b0, S0, S1) CVT(b1, S2, S3) CVT(b2, S4, S5) CVT(b3, S6, S7) \
    if ((JR) + 2 < 16) { LOADSET((JR) + 2, S0, S1, S2, S3, S4, S5, S6, S7) } \
    const float ms = ((msk >> (JR)) & 1) ? 1.f : 0.f; \
    const float* hjg = hjp + (size_t)(jbase + (JR)) * DD + wave * 32 + q * 4; \
    f32x4 hv0 = *(const f32x4*)(hjg); \
    f32x4 hv1 = *(const f32x4*)(hjg + 16); \
    f32x4 p0 = {0.f, 0.f, 0.f, 0.f}, p1 = p0; \
    p0 = mfma16(aw00, b0, p0); p1 = mfma16(aw10, b0, p1); \
    p0 = mfma16(aw01, b1, p0); p1 = mfma16(aw11, b1, p1); \
    p0 = mfma16(aw02, b2, p0); p1 = mfma16(aw12, b2, p1); \
    p0 = mfma16(aw03, b3, p0); p1 = mfma16(aw13, b3, p1); \
    _Pragma("unroll") \
    for (int r = 0; r < 4; r++) { \
      float v0 = p0[r] + hv0[r]; \
      float v1 = p1[r] + hv1[r]; \
      t0[r] += ms * v0 * __builtin_amdgcn_rcpf(1.f + __expf(-v0)); \
      t1[r] += ms * v1 * __builtin_amdgcn_rcpf(1.f + __expf(-v1)); \
    } }

  #pragma unroll 1
  for (int jj = 0; jj < 16; jj += 2) {
    STEP(jj,     X0, X1, X2, X3, X4, X5, X6, X7)
    STEP(jj + 1, Y0, Y1, Y2, Y3, Y4, Y5, Y6, Y7)
  }
  #undef STEP
  #undef LOADSET

  // direct per-wave e-slice write (no cross-wave reduction needed)
  float* pp = partial + ((size_t)jc * NN + irow + l15) * DD + wave * 32 + q * 4;
  *(f32x4*)pp = t0;
  *(f32x4*)(pp + 16) = t1;
}

// ------- phase 2: T-reduce + GEMM2(f32) + update MLP + LayerNorm -------
__global__ void k_update(const float* __restrict__ h, const float* __restrict__ partial,
                         const float* __restrict__ w2, const float* __restrict__ b2,
                         const float* __restrict__ cnt,
                         const float* __restrict__ uw1, const float* __restrict__ ub1,
                         const float* __restrict__ uw2, const float* __restrict__ ub2,
                         const float* __restrict__ g, const float* __restrict__ bb,
                         float* __restrict__ out) {
  __shared__ float Trow[128];
  __shared__ float uin[256];
  __shared__ float zl[128];
  __shared__ float ss[4];
  int i = blockIdx.x, t = threadIdx.x;
  float hv = h[i * 128 + t];
  float ts = 0.f;
  #pragma unroll
  for (int c = 0; c < 32; c++) ts += partial[((size_t)c * NN + i) * DD + t];
  Trow[t] = ts;
  __syncthreads();
  float a0 = cnt[i] * b2[t], a1 = 0.f;
  #pragma unroll 16
  for (int e = 0; e < 128; e += 2) {
    a0 += Trow[e] * w2[e * 128 + t];
    a1 += Trow[e + 1] * w2[(e + 1) * 128 + t];
  }
  uin[t] = hv;
  uin[128 + t] = a0 + a1;
  __syncthreads();
  float z0 = ub1[t], z1 = 0.f, z2 = 0.f, z3 = 0.f;
  #pragma unroll 16
  for (int k = 0; k < 256; k += 4) {
    z0 += uin[k] * uw1[k * 128 + t];
    z1 += uin[k + 1] * uw1[(k + 1) * 128 + t];
    z2 += uin[k + 2] * uw1[(k + 2) * 128 + t];
    z3 += uin[k + 3] * uw1[(k + 3) * 128 + t];
  }
  float z = (z0 + z1) + (z2 + z3);
  z = z / (1.f + __expf(-z));
  zl[t] = z;
  __syncthreads();
  float d0 = ub2[t], d1 = 0.f;
  #pragma unroll 16
  for (int k = 0; k < 128; k += 2) {
    d0 += zl[k] * uw2[k * 128 + t];
    d1 += zl[k + 1] * uw2[(k + 1) * 128 + t];
  }
  float x = hv + d0 + d1;
  float s1 = x, s2 = x * x;
  #pragma unroll
  for (int off = 32; off > 0; off >>= 1) {
    s1 += __shfl_down(s1, off, 64);
    s2 += __shfl_down(s2, off, 64);
  }
  if ((t & 63) == 0) { ss[(t >> 6) * 2] = s1; ss[(t >> 6) * 2 + 1] = s2; }
  __syncthreads();
  s1 = ss[0] + ss[2];
  s2 = ss[1] + ss[3];
  float mu = s1 * (1.f / 128.f);
  float var = s2 * (1.f / 128.f) - mu * mu;
  out[i * 128 + t] = (x - mu) * rsqrtf(var + 1e-5f) * g[t] + bb[t];
}

extern "C" void kernel_launch(void* const* d_in, const int* in_sizes, int n_in,
                              void* d_out, int out_size, void* d_ws, size_t ws_size,
                              hipStream_t stream) {
  const float* h      = (const float*)d_in[0];
  const float* rel    = (const float*)d_in[1];
  const int*   emask  = (const int*)d_in[2];
  const float* msg_w1 = (const float*)d_in[3];
  const float* msg_b1 = (const float*)d_in[4];
  const float* msg_w2 = (const float*)d_in[5];
  const float* msg_b2 = (const float*)d_in[6];
  const float* upd_w1 = (const float*)d_in[7];
  const float* upd_b1 = (const float*)d_in[8];
  const float* upd_w2 = (const float*)d_in[9];
  const float* upd_b2 = (const float*)d_in[10];
  const float* ln_g   = (const float*)d_in[11];
  const float* ln_b   = (const float*)d_in[12];
  float* out = (float*)d_out;

  char* ws = (char*)d_ws;
  float*  hjp     = (float*)ws;                        // 262144 B
  __bf16* w1t     = (__bf16*)(ws + 262144);            // 32768 B
  float*  cnt     = (float*)(ws + 262144 + 32768);     // 2048 B
  float*  partial = (float*)(ws + 262144 + 36864);     // 32*512*128*4 = 8 MiB

  k_pre<<<512, 128, 0, stream>>>(h, msg_w1, msg_b1, emask, w1t, hjp, cnt);
  k_main<<<1024, 256, 0, stream>>>(rel, emask, hjp, w1t, partial);
  k_update<<<512, 128, 0, stream>>>(h, partial, msg_w2, msg_b2, cnt,
                                    upd_w1, upd_b1, upd_w2, upd_b2,
                                    ln_g, ln_b, out);
}

// Round 22
// 46.909 us; speedup vs baseline: 1.3987x; 1.3987x over previous
//
#include <hip/hip_runtime.h>
#include <hip/hip_bf16.h>

#define NN 512
#define DD 128

typedef __bf16 bf16x8 __attribute__((ext_vector_type(8)));
typedef float f32x4 __attribute__((ext_vector_type(4)));

static __device__ __forceinline__ f32x4 mfma16(bf16x8 a, bf16x8 b, f32x4 c) {
  return __builtin_amdgcn_mfma_f32_16x16x32_bf16(a, b, c, 0, 0, 0);
}

// -------- phase 0 (fused): w1t transpose + hjp + cnt --------
__global__ void k_pre(const float* __restrict__ h,
                      const float* __restrict__ msg_w1,
                      const float* __restrict__ msg_b1,
                      const int* __restrict__ emask,
                      __bf16* __restrict__ w1t, float* __restrict__ hjp,
                      float* __restrict__ cnt) {
  __shared__ float hr[128];
  __shared__ int csum;
  int j = blockIdx.x, t = threadIdx.x;
  if (t == 0) csum = 0;
  hr[t] = h[j * 128 + t];
  __syncthreads();
  float a0 = msg_b1[t], a1 = 0.f;
  #pragma unroll 16
  for (int k = 0; k < 128; k += 2) {
    a0 += hr[k] * msg_w1[k * 128 + t];
    a1 += hr[k + 1] * msg_w1[(k + 1) * 128 + t];
  }
  hjp[j * 128 + t] = a0 + a1;
  if (t < 32) {
    int tt = j * 32 + t;
    int e = tt >> 7, k = tt & 127;
    w1t[e * 128 + k] = (__bf16)msg_w1[(128 + k) * 128 + e];
  }
  int s = 0;
  #pragma unroll
  for (int r = 0; r < 4; r++) s += emask[(t * 4 + r) * NN + j] ? 1 : 0;
  #pragma unroll
  for (int off = 32; off > 0; off >>= 1) s += __shfl_down(s, off, 64);
  if ((t & 63) == 0) atomicAdd(&csum, s);
  __syncthreads();
  if (t == 0) cnt[j] = (float)csum;
}

// ---------------- phase 1: T[i][e] = sum_j mask[j,i]*silu(pre[j,i,e]) ----
// BATCHED-BARRIER version of R19 (verified 43.1us). Root cause analysis:
// __syncthreads() compiles to s_waitcnt vmcnt(0) lgkmcnt(0); s_barrier --
// so R19's 16 per-step barriers force-drained every prefetch one step
// after issue (the depth-4 pipeline never ran deep). Fix: batch 4 j's per
// barrier. Two buffers x 4 bf16 tiles (34KB). Batch b: barrier ->
// publish rows 4(b+1).. (ds_write from 4 static reg sets) -> issue loads
// rows 4(b+2).. -> compute rows 4b..4b+3 (scheduler free to pipeline the
// 4 COMPUTEs; no intervening barriers). Barriers 16 -> 4; each load gets
// a full batch (~1000cy) before its drain. Race audit: buffer (b+1)&1
// published at batch b was last read at batch b-1; barrier b separates.
// hv from global hjp post-chain (R20-proven neutral; saves 8KB LDS ->
// 4 blocks/CU). Masking invariants unchanged: regs zero-initialized,
// stale contents finite, ms=0 masks exactly -> bit-identical output.
// (256,2) = cap 256, the only spill-free cap (R1-R10 allocator law).
#define CVT(bf, xa, xb) { \
  bf[0] = (__bf16)xa[0]; bf[1] = (__bf16)xa[1]; \
  bf[2] = (__bf16)xa[2]; bf[3] = (__bf16)xa[3]; \
  bf[4] = (__bf16)xb[0]; bf[5] = (__bf16)xb[1]; \
  bf[6] = (__bf16)xb[2]; bf[7] = (__bf16)xb[3]; }

__global__ __launch_bounds__(256, 2) void k_main(
    const float* __restrict__ rel, const int* __restrict__ emask,
    const float* __restrict__ hjp, const __bf16* __restrict__ w1t_g,
    float* __restrict__ partial) {
  // tile[buf][slot][row][col]: 2 bufs x 4 slots x 16 x 136 bf16 = 34816 B
  __shared__ __align__(16) __bf16 tile[2 * 4 * 16 * 136];
  __shared__ float mk[256];
  const int tid = threadIdx.x;
  const int wave = tid >> 6;
  const int lane = tid & 63;
  const int l15 = lane & 15;
  const int q = lane >> 4;

  const int it = blockIdx.x >> 5;    // 0..31 : 16-row i-tile
  const int jc = blockIdx.x & 31;    // 0..31 : 16-col j-chunk
  const int irow = it * 16;
  const int jbase = jc * 16;

  // mask table
  mk[tid] = emask[(size_t)(jbase + (tid >> 4)) * NN + irow + (tid & 15)] ? 1.f : 0.f;

  // wave-private w1 fragments for e-slice [32w, 32w+32)
  bf16x8 aw00, aw01, aw02, aw03, aw10, aw11, aw12, aw13;
  {
    const __bf16* b0 = w1t_g + (wave * 32 + l15) * 128 + q * 8;
    aw00 = *(const bf16x8*)(b0);
    aw01 = *(const bf16x8*)(b0 + 32);
    aw02 = *(const bf16x8*)(b0 + 64);
    aw03 = *(const bf16x8*)(b0 + 96);
    const __bf16* b1 = b0 + 16 * 128;
    aw10 = *(const bf16x8*)(b1);
    aw11 = *(const bf16x8*)(b1 + 32);
    aw12 = *(const bf16x8*)(b1 + 64);
    aw13 = *(const bf16x8*)(b1 + 96);
  }

  // t0[r] = T[i=l15][e=32w+q*4+r], t1 = +16
  f32x4 t0 = {0.f, 0.f, 0.f, 0.f}, t1 = t0;

  // staging role: thread covers row srow, 8-float chunk schunk
  const int srow = tid >> 4;
  const int schunk = tid & 15;
  const float* sb = rel + ((size_t)jbase * NN + irow + srow) * DD + schunk * 8;
  __bf16* sd = tile + srow * 136 + schunk * 8;

  __syncthreads();   // mk visible

  // 4 static staging sets, zeroed once (stale finite; ms=0 masks exactly)
  f32x4 xa0 = {0.f, 0.f, 0.f, 0.f}, xb0 = xa0;
  f32x4 xa1 = xa0, xb1 = xa0;
  f32x4 xa2 = xa0, xb2 = xa0;
  f32x4 xa3 = xa0, xb3 = xa0;

  #define LOADJ(J, XA, XB) \
    if (mk[(J) * 16 + srow] != 0.f) { \
      const float* s = sb + (size_t)(J) * (NN * DD); \
      XA = *(const f32x4*)s; XB = *(const f32x4*)(s + 4); \
    }

  // PUB: publish set to tile[buf((J)>>2&1)][slot(J&3)]
  #define PUB(J, XA, XB) { \
    bf16x8 pub; \
    CVT(pub, XA, XB) \
    *(bf16x8*)(sd + ((((J) >> 2) & 1) ? 8704 : 0) + ((J) & 3) * 2176) = pub; \
  }

  // COMPUTE: fragments from tile; MFMA chain; hv (global, post-chain);
  // silu; masked accumulate.
  #define COMPUTE(J) { \
    const float ms = mk[(J) * 16 + l15]; \
    const __bf16* tp = tile + ((((J) >> 2) & 1) ? 8704 : 0) + ((J) & 3) * 2176 \
                       + l15 * 136 + q * 8; \
    bf16x8 b0 = *(const bf16x8*)(tp); \
    bf16x8 b1 = *(const bf16x8*)(tp + 32); \
    bf16x8 b2 = *(const bf16x8*)(tp + 64); \
    bf16x8 b3 = *(const bf16x8*)(tp + 96); \
    const float* hjg = hjp + (size_t)(jbase + (J)) * DD + wave * 32 + q * 4; \
    f32x4 hv0 = *(const f32x4*)(hjg); \
    f32x4 hv1 = *(const f32x4*)(hjg + 16); \
    f32x4 p0 = {0.f, 0.f, 0.f, 0.f}, p1 = p0; \
    p0 = mfma16(aw00, b0, p0); p1 = mfma16(aw10, b0, p1); \
    p0 = mfma16(aw01, b1, p0); p1 = mfma16(aw11, b1, p1); \
    p0 = mfma16(aw02, b2, p0); p1 = mfma16(aw12, b2, p1); \
    p0 = mfma16(aw03, b3, p0); p1 = mfma16(aw13, b3, p1); \
    _Pragma("unroll") \
    for (int r = 0; r < 4; r++) { \
      float v0 = p0[r] + hv0[r]; \
      float v1 = p1[r] + hv1[r]; \
      t0[r] += ms * v0 * __builtin_amdgcn_rcpf(1.f + __expf(-v0)); \
      t1[r] += ms * v1 * __builtin_amdgcn_rcpf(1.f + __expf(-v1)); \
    } }

  // prologue: rows 0-3 -> sets -> buf0; reload rows 4-7 -> sets
  LOADJ(0, xa0, xb0) LOADJ(1, xa1, xb1) LOADJ(2, xa2, xb2) LOADJ(3, xa3, xb3)
  PUB(0, xa0, xb0) PUB(1, xa1, xb1) PUB(2, xa2, xb2) PUB(3, xa3, xb3)
  LOADJ(4, xa0, xb0) LOADJ(5, xa1, xb1) LOADJ(6, xa2, xb2) LOADJ(7, xa3, xb3)

  // batch 0: publish rows 4-7 -> buf1; load rows 8-11; compute rows 0-3
  __syncthreads();
  PUB(4, xa0, xb0) PUB(5, xa1, xb1) PUB(6, xa2, xb2) PUB(7, xa3, xb3)
  LOADJ(8, xa0, xb0) LOADJ(9, xa1, xb1) LOADJ(10, xa2, xb2) LOADJ(11, xa3, xb3)
  COMPUTE(0) COMPUTE(1) COMPUTE(2) COMPUTE(3)

  // batch 1: publish rows 8-11 -> buf0; load rows 12-15; compute rows 4-7
  __syncthreads();
  PUB(8, xa0, xb0) PUB(9, xa1, xb1) PUB(10, xa2, xb2) PUB(11, xa3, xb3)
  LOADJ(12, xa0, xb0) LOADJ(13, xa1, xb1) LOADJ(14, xa2, xb2) LOADJ(15, xa3, xb3)
  COMPUTE(4) COMPUTE(5) COMPUTE(6) COMPUTE(7)

  // batch 2: publish rows 12-15 -> buf1; compute rows 8-11
  __syncthreads();
  PUB(12, xa0, xb0) PUB(13, xa1, xb1) PUB(14, xa2, xb2) PUB(15, xa3, xb3)
  COMPUTE(8) COMPUTE(9) COMPUTE(10) COMPUTE(11)

  // batch 3: compute rows 12-15
  __syncthreads();
  COMPUTE(12) COMPUTE(13) COMPUTE(14) COMPUTE(15)

  #undef COMPUTE
  #undef PUB
  #undef LOADJ

  // direct per-wave e-slice write (no cross-wave reduction needed)
  float* pp = partial + ((size_t)jc * NN + irow + l15) * DD + wave * 32 + q * 4;
  *(f32x4*)pp = t0;
  *(f32x4*)(pp + 16) = t1;
}

// ------- phase 2: T-reduce + GEMM2(f32) + update MLP + LayerNorm -------
__global__ void k_update(const float* __restrict__ h, const float* __restrict__ partial,
                         const float* __restrict__ w2, const float* __restrict__ b2,
                         const float* __restrict__ cnt,
                         const float* __restrict__ uw1, const float* __restrict__ ub1,
                         const float* __restrict__ uw2, const float* __restrict__ ub2,
                         const float* __restrict__ g, const float* __restrict__ bb,
                         float* __restrict__ out) {
  __shared__ float Trow[128];
  __shared__ float uin[256];
  __shared__ float zl[128];
  __shared__ float ss[4];
  int i = blockIdx.x, t = threadIdx.x;
  float hv = h[i * 128 + t];
  float ts = 0.f;
  #pragma unroll
  for (int c = 0; c < 32; c++) ts += partial[((size_t)c * NN + i) * DD + t];
  Trow[t] = ts;
  __syncthreads();
  float a0 = cnt[i] * b2[t], a1 = 0.f;
  #pragma unroll 16
  for (int e = 0; e < 128; e += 2) {
    a0 += Trow[e] * w2[e * 128 + t];
    a1 += Trow[e + 1] * w2[(e + 1) * 128 + t];
  }
  uin[t] = hv;
  uin[128 + t] = a0 + a1;
  __syncthreads();
  float z0 = ub1[t], z1 = 0.f, z2 = 0.f, z3 = 0.f;
  #pragma unroll 16
  for (int k = 0; k < 256; k += 4) {
    z0 += uin[k] * uw1[k * 128 + t];
    z1 += uin[k + 1] * uw1[(k + 1) * 128 + t];
    z2 += uin[k + 2] * uw1[(k + 2) * 128 + t];
    z3 += uin[k + 3] * uw1[(k + 3) * 128 + t];
  }
  float z = (z0 + z1) + (z2 + z3);
  z = z / (1.f + __expf(-z));
  zl[t] = z;
  __syncthreads();
  float d0 = ub2[t], d1 = 0.f;
  #pragma unroll 16
  for (int k = 0; k < 128; k += 2) {
    d0 += zl[k] * uw2[k * 128 + t];
    d1 += zl[k + 1] * uw2[(k + 1) * 128 + t];
  }
  float x = hv + d0 + d1;
  float s1 = x, s2 = x * x;
  #pragma unroll
  for (int off = 32; off > 0; off >>= 1) {
    s1 += __shfl_down(s1, off, 64);
    s2 += __shfl_down(s2, off, 64);
  }
  if ((t & 63) == 0) { ss[(t >> 6) * 2] = s1; ss[(t >> 6) * 2 + 1] = s2; }
  __syncthreads();
  s1 = ss[0] + ss[2];
  s2 = ss[1] + ss[3];
  float mu = s1 * (1.f / 128.f);
  float var = s2 * (1.f / 128.f) - mu * mu;
  out[i * 128 + t] = (x - mu) * rsqrtf(var + 1e-5f) * g[t] + bb[t];
}

extern "C" void kernel_launch(void* const* d_in, const int* in_sizes, int n_in,
                              void* d_out, int out_size, void* d_ws, size_t ws_size,
                              hipStream_t stream) {
  const float* h      = (const float*)d_in[0];
  const float* rel    = (const float*)d_in[1];
  const int*   emask  = (const int*)d_in[2];
  const float* msg_w1 = (const float*)d_in[3];
  const float* msg_b1 = (const float*)d_in[4];
  const float* msg_w2 = (const float*)d_in[5];
  const float* msg_b2 = (const float*)d_in[6];
  const float* upd_w1 = (const float*)d_in[7];
  const float* upd_b1 = (const float*)d_in[8];
  const float* upd_w2 = (const float*)d_in[9];
  const float* upd_b2 = (const float*)d_in[10];
  const float* ln_g   = (const float*)d_in[11];
  const float* ln_b   = (const float*)d_in[12];
  float* out = (float*)d_out;

  char* ws = (char*)d_ws;
  float*  hjp     = (float*)ws;                        // 262144 B
  __bf16* w1t     = (__bf16*)(ws + 262144);            // 32768 B
  float*  cnt     = (float*)(ws + 262144 + 32768);     // 2048 B
  float*  partial = (float*)(ws + 262144 + 36864);     // 32*512*128*4 = 8 MiB

  k_pre<<<512, 128, 0, stream>>>(h, msg_w1, msg_b1, emask, w1t, hjp, cnt);
  k_main<<<1024, 256, 0, stream>>>(rel, emask, hjp, w1t, partial);
  k_update<<<512, 128, 0, stream>>>(h, partial, msg_w2, msg_b2, cnt,
                                    upd_w1, upd_b1, upd_w2, upd_b2,
                                    ln_g, ln_b, out);
}

// Round 23
// 43.039 us; speedup vs baseline: 1.5245x; 1.0899x over previous
//
#include <hip/hip_runtime.h>
#include <hip/hip_bf16.h>

#define NN 512
#define DD 128

typedef __bf16 bf16x8 __attribute__((ext_vector_type(8)));
typedef float f32x4 __attribute__((ext_vector_type(4)));

static __device__ __forceinline__ f32x4 mfma16(bf16x8 a, bf16x8 b, f32x4 c) {
  return __builtin_amdgcn_mfma_f32_16x16x32_bf16(a, b, c, 0, 0, 0);
}

// -------- phase 0 (fused): w1t transpose + hjp + cnt --------
__global__ void k_pre(const float* __restrict__ h,
                      const float* __restrict__ msg_w1,
                      const float* __restrict__ msg_b1,
                      const int* __restrict__ emask,
                      __bf16* __restrict__ w1t, float* __restrict__ hjp,
                      float* __restrict__ cnt) {
  __shared__ float hr[128];
  __shared__ int csum;
  int j = blockIdx.x, t = threadIdx.x;
  if (t == 0) csum = 0;
  hr[t] = h[j * 128 + t];
  __syncthreads();
  float a0 = msg_b1[t], a1 = 0.f;
  #pragma unroll 16
  for (int k = 0; k < 128; k += 2) {
    a0 += hr[k] * msg_w1[k * 128 + t];
    a1 += hr[k + 1] * msg_w1[(k + 1) * 128 + t];
  }
  hjp[j * 128 + t] = a0 + a1;
  // w1t[e][k] = msg_w1[128+k][e] : 32 elements per block
  if (t < 32) {
    int tt = j * 32 + t;
    int e = tt >> 7, k = tt & 127;
    w1t[e * 128 + k] = (__bf16)msg_w1[(128 + k) * 128 + e];
  }
  // cnt[j] = sum_r emask[r][j]
  int s = 0;
  #pragma unroll
  for (int r = 0; r < 4; r++) s += emask[(t * 4 + r) * NN + j] ? 1 : 0;
  #pragma unroll
  for (int off = 32; off > 0; off >>= 1) s += __shfl_down(s, off, 64);
  if ((t & 63) == 0) atomicAdd(&csum, s);
  __syncthreads();
  if (t == 0) cnt[j] = (float)csum;
}

// ---------------- phase 1: T[i][e] = sum_j mask[j,i]*silu(pre[j,i,e]) ----
// EXACT R19 structure (verified 43.1us, reproducible) with ONE change:
// the 16 in-loop __syncthreads() -> lgkmcnt(0)-only barriers (T4).
// __syncthreads compiles to s_waitcnt vmcnt(0) lgkmcnt(0); s_barrier --
// the vmcnt(0) drains prefetches issued ONE step earlier (~300cy) against
// ~900cy HBM latency => ~600cy stall/step; the depth-4 pipeline never ran
// deep (R22's batched variant confirmed schedule-shape fixes regress).
// LDS correctness needs only lgkmcnt(0): (1) publish ds_write completes
// before the wave's barrier -> visible to readers after it; (2) COMPUTE's
// ds_reads are lgkm ops, drained by the same wait before the barrier that
// precedes the buffer's overwrite; (3) global prefetch regs are drained
// by the compiler's auto vmcnt(N) before their CVT use, 4 steps later --
// loads now genuinely rest ~4 steps. Memory clobbers pin ds-op ordering
// around the raw barrier (rule #18 hygiene).
// (256,2) = cap 256, the only spill-free cap (R1-R10 allocator law).
#define BARRIER_LGKM() { \
    asm volatile("s_waitcnt lgkmcnt(0)" ::: "memory"); \
    __builtin_amdgcn_s_barrier(); \
    asm volatile("" ::: "memory"); }

#define CVT(bf, xa, xb) { \
  bf[0] = (__bf16)xa[0]; bf[1] = (__bf16)xa[1]; \
  bf[2] = (__bf16)xa[2]; bf[3] = (__bf16)xa[3]; \
  bf[4] = (__bf16)xb[0]; bf[5] = (__bf16)xb[1]; \
  bf[6] = (__bf16)xb[2]; bf[7] = (__bf16)xb[3]; }

__global__ __launch_bounds__(256, 2) void k_main(
    const float* __restrict__ rel, const int* __restrict__ emask,
    const float* __restrict__ hjp, const __bf16* __restrict__ w1t_g,
    float* __restrict__ partial) {
  __shared__ __align__(16) __bf16 tile[2 * 16 * 136];
  __shared__ float mk[256];
  __shared__ __align__(16) float hjl[16 * 128];
  const int tid = threadIdx.x;
  const int wave = tid >> 6;
  const int lane = tid & 63;
  const int l15 = lane & 15;
  const int q = lane >> 4;

  const int it = blockIdx.x >> 5;    // 0..31 : 16-row i-tile
  const int jc = blockIdx.x & 31;    // 0..31 : 16-col j-chunk
  const int irow = it * 16;
  const int jbase = jc * 16;

  // mask table + hjp slice staging
  mk[tid] = emask[(size_t)(jbase + (tid >> 4)) * NN + irow + (tid & 15)] ? 1.f : 0.f;
  {
    int r2 = tid >> 4, c8 = (tid & 15) * 8;
    const float* hsrc = hjp + (size_t)(jbase + r2) * DD + c8;
    *(f32x4*)(hjl + r2 * 128 + c8) = *(const f32x4*)hsrc;
    *(f32x4*)(hjl + r2 * 128 + c8 + 4) = *(const f32x4*)(hsrc + 4);
  }

  // wave-private w1 fragments for e-slice [32w, 32w+32)
  bf16x8 aw00, aw01, aw02, aw03, aw10, aw11, aw12, aw13;
  {
    const __bf16* b0 = w1t_g + (wave * 32 + l15) * 128 + q * 8;
    aw00 = *(const bf16x8*)(b0);
    aw01 = *(const bf16x8*)(b0 + 32);
    aw02 = *(const bf16x8*)(b0 + 64);
    aw03 = *(const bf16x8*)(b0 + 96);
    const __bf16* b1 = b0 + 16 * 128;
    aw10 = *(const bf16x8*)(b1);
    aw11 = *(const bf16x8*)(b1 + 32);
    aw12 = *(const bf16x8*)(b1 + 64);
    aw13 = *(const bf16x8*)(b1 + 96);
  }

  // t0[r] = T[i=l15][e=32w+q*4+r], t1 = +16
  f32x4 t0 = {0.f, 0.f, 0.f, 0.f}, t1 = t0;

  // staging role: thread covers row srow, 8-float chunk schunk
  const int srow = tid >> 4;
  const int schunk = tid & 15;
  const float* sb = rel + ((size_t)jbase * NN + irow + srow) * DD + schunk * 8;
  __bf16* sd = tile + srow * 136 + schunk * 8;

  __syncthreads();   // mk + hjl visible (full barrier, once)

  // prologue: zero all 4 staging sets; stage row0 -> tile[0];
  // load rows 1..4 -> A..D (predicated; stale contents finite; ms=0 masks).
  f32x4 xa0 = {0.f, 0.f, 0.f, 0.f}, xb0 = xa0;
  f32x4 xa1 = xa0, xb1 = xa0;
  f32x4 xa2 = xa0, xb2 = xa0;
  f32x4 xa3 = xa0, xb3 = xa0;
  {
    f32x4 ra = xa0, rb = xa0;
    if (mk[srow] != 0.f) { ra = *(const f32x4*)sb; rb = *(const f32x4*)(sb + 4); }
    bf16x8 pub;
    CVT(pub, ra, rb)
    *(bf16x8*)sd = pub;
    if (mk[16 + srow] != 0.f) {
      const float* s = sb + (size_t)NN * DD;
      xa0 = *(const f32x4*)s; xb0 = *(const f32x4*)(s + 4);
    }
    if (mk[32 + srow] != 0.f) {
      const float* s = sb + 2 * (size_t)NN * DD;
      xa1 = *(const f32x4*)s; xb1 = *(const f32x4*)(s + 4);
    }
    if (mk[48 + srow] != 0.f) {
      const float* s = sb + 3 * (size_t)NN * DD;
      xa2 = *(const f32x4*)s; xb2 = *(const f32x4*)(s + 4);
    }
    if (mk[64 + srow] != 0.f) {
      const float* s = sb + 4 * (size_t)NN * DD;
      xa3 = *(const f32x4*)s; xb3 = *(const f32x4*)(s + 4);
    }
  }

  #define COMPUTE(JROW) { \
    const float ms = mk[(JROW) * 16 + l15]; \
    const __bf16* tp = tile + (((JROW) & 1) ? 2176 : 0) + l15 * 136 + q * 8; \
    bf16x8 bf0 = *(const bf16x8*)(tp); \
    bf16x8 bf1 = *(const bf16x8*)(tp + 32); \
    bf16x8 bf2 = *(const bf16x8*)(tp + 64); \
    bf16x8 bf3 = *(const bf16x8*)(tp + 96); \
    f32x4 p0 = {0.f, 0.f, 0.f, 0.f}, p1 = p0; \
    p0 = mfma16(aw00, bf0, p0); p1 = mfma16(aw10, bf0, p1); \
    p0 = mfma16(aw01, bf1, p0); p1 = mfma16(aw11, bf1, p1); \
    p0 = mfma16(aw02, bf2, p0); p1 = mfma16(aw12, bf2, p1); \
    p0 = mfma16(aw03, bf3, p0); p1 = mfma16(aw13, bf3, p1); \
    const float* hj = hjl + (JROW) * 128 + wave * 32 + q * 4; \
    f32x4 hv0 = *(const f32x4*)(hj); \
    f32x4 hv1 = *(const f32x4*)(hj + 16); \
    _Pragma("unroll") \
    for (int r = 0; r < 4; r++) { \
      float v0 = p0[r] + hv0[r]; \
      float v1 = p1[r] + hv1[r]; \
      t0[r] += ms * v0 * __builtin_amdgcn_rcpf(1.f + __expf(-v0)); \
      t1[r] += ms * v1 * __builtin_amdgcn_rcpf(1.f + __expf(-v1)); \
    } }

  // STEP(JR, set): lgkm-barrier; publish row JR+1 from set; load row
  // JR+5 -> set; compute row JR. Set rotation: step JR uses set JR&3
  // (reused at JR+4, holding row JR+5). Global prefetches persist across
  // barriers; drained by compiler vmcnt before the CVT use 4 steps later.
  #define STEP(JR, XA, XB) { \
    BARRIER_LGKM() \
    if ((JR) + 1 < 16) { \
      bf16x8 pub; \
      CVT(pub, XA, XB) \
      *(bf16x8*)(sd + ((((JR) + 1) & 1) ? 2176 : 0)) = pub; \
    } \
    if ((JR) + 5 < 16) { \
      if (mk[((JR) + 5) * 16 + srow] != 0.f) { \
        const float* s = sb + (size_t)((JR) + 5) * NN * DD; \
        XA = *(const f32x4*)s; XB = *(const f32x4*)(s + 4); \
      } \
    } \
    COMPUTE(JR) }

  #pragma unroll 1
  for (int jj = 0; jj < 16; jj += 4) {
    STEP(jj,     xa0, xb0)
    STEP(jj + 1, xa1, xb1)
    STEP(jj + 2, xa2, xb2)
    STEP(jj + 3, xa3, xb3)
  }
  #undef STEP
  #undef COMPUTE

  // direct per-wave e-slice write (no cross-wave reduction needed)
  float* pp = partial + ((size_t)jc * NN + irow + l15) * DD + wave * 32 + q * 4;
  *(f32x4*)pp = t0;
  *(f32x4*)(pp + 16) = t1;
}

// ------- phase 2: T-reduce + GEMM2(f32) + update MLP + LayerNorm -------
__global__ void k_update(const float* __restrict__ h, const float* __restrict__ partial,
                         const float* __restrict__ w2, const float* __restrict__ b2,
                         const float* __restrict__ cnt,
                         const float* __restrict__ uw1, const float* __restrict__ ub1,
                         const float* __restrict__ uw2, const float* __restrict__ ub2,
                         const float* __restrict__ g, const float* __restrict__ bb,
                         float* __restrict__ out) {
  __shared__ float Trow[128];
  __shared__ float uin[256];
  __shared__ float zl[128];
  __shared__ float ss[4];
  int i = blockIdx.x, t = threadIdx.x;
  float hv = h[i * 128 + t];
  float ts = 0.f;
  #pragma unroll
  for (int c = 0; c < 32; c++) ts += partial[((size_t)c * NN + i) * DD + t];
  Trow[t] = ts;
  __syncthreads();
  float a0 = cnt[i] * b2[t], a1 = 0.f;
  #pragma unroll 16
  for (int e = 0; e < 128; e += 2) {
    a0 += Trow[e] * w2[e * 128 + t];
    a1 += Trow[e + 1] * w2[(e + 1) * 128 + t];
  }
  uin[t] = hv;
  uin[128 + t] = a0 + a1;
  __syncthreads();
  float z0 = ub1[t], z1 = 0.f, z2 = 0.f, z3 = 0.f;
  #pragma unroll 16
  for (int k = 0; k < 256; k += 4) {
    z0 += uin[k] * uw1[k * 128 + t];
    z1 += uin[k + 1] * uw1[(k + 1) * 128 + t];
    z2 += uin[k + 2] * uw1[(k + 2) * 128 + t];
    z3 += uin[k + 3] * uw1[(k + 3) * 128 + t];
  }
  float z = (z0 + z1) + (z2 + z3);
  z = z / (1.f + __expf(-z));
  zl[t] = z;
  __syncthreads();
  float d0 = ub2[t], d1 = 0.f;
  #pragma unroll 16
  for (int k = 0; k < 128; k += 2) {
    d0 += zl[k] * uw2[k * 128 + t];
    d1 += zl[k + 1] * uw2[(k + 1) * 128 + t];
  }
  float x = hv + d0 + d1;
  float s1 = x, s2 = x * x;
  #pragma unroll
  for (int off = 32; off > 0; off >>= 1) {
    s1 += __shfl_down(s1, off, 64);
    s2 += __shfl_down(s2, off, 64);
  }
  if ((t & 63) == 0) { ss[(t >> 6) * 2] = s1; ss[(t >> 6) * 2 + 1] = s2; }
  __syncthreads();
  s1 = ss[0] + ss[2];
  s2 = ss[1] + ss[3];
  float mu = s1 * (1.f / 128.f);
  float var = s2 * (1.f / 128.f) - mu * mu;
  out[i * 128 + t] = (x - mu) * rsqrtf(var + 1e-5f) * g[t] + bb[t];
}

extern "C" void kernel_launch(void* const* d_in, const int* in_sizes, int n_in,
                              void* d_out, int out_size, void* d_ws, size_t ws_size,
                              hipStream_t stream) {
  const float* h      = (const float*)d_in[0];
  const float* rel    = (const float*)d_in[1];
  const int*   emask  = (const int*)d_in[2];
  const float* msg_w1 = (const float*)d_in[3];
  const float* msg_b1 = (const float*)d_in[4];
  const float* msg_w2 = (const float*)d_in[5];
  const float* msg_b2 = (const float*)d_in[6];
  const float* upd_w1 = (const float*)d_in[7];
  const float* upd_b1 = (const float*)d_in[8];
  const float* upd_w2 = (const float*)d_in[9];
  const float* upd_b2 = (const float*)d_in[10];
  const float* ln_g   = (const float*)d_in[11];
  const float* ln_b   = (const float*)d_in[12];
  float* out = (float*)d_out;

  char* ws = (char*)d_ws;
  float*  hjp     = (float*)ws;                        // 262144 B
  __bf16* w1t     = (__bf16*)(ws + 262144);            // 32768 B
  float*  cnt     = (float*)(ws + 262144 + 32768);     // 2048 B
  float*  partial = (float*)(ws + 262144 + 36864);     // 32*512*128*4 = 8 MiB

  k_pre<<<512, 128, 0, stream>>>(h, msg_w1, msg_b1, emask, w1t, hjp, cnt);
  k_main<<<1024, 256, 0, stream>>>(rel, emask, hjp, w1t, partial);
  k_update<<<512, 128, 0, stream>>>(h, partial, msg_w2, msg_b2, cnt,
                                    upd_w1, upd_b1, upd_w2, upd_b2,
                                    ln_g, ln_b, out);
}